// Round 1
// 224.356 us; speedup vs baseline: 1.0063x; 1.0063x over previous
//
#include <hip/hip_runtime.h>
#include <hip/hip_bf16.h>

// Problem: B,W,H,L = 2,32,32,32 -> N=65536 voxels; D=512, E=64 heads, V=16.
// Round-12: R11 counters showed latency-bound everything-idle (Occ 14.5%,
// BW 12%, MfmaUtil 0.6%): the global_load_lds staging path full-drains
// vmcnt(0) per 8KB round and the 512-block grid pins occupancy at <=8
// waves/CU with no refill to cover head imbalance. Replace DMA staging with
// direct-to-VGPR A-fragment loads (32 independent dwordx4 per tile, compiler
// emits counted vmcnt waits), drop 40KB of LDS (21KB left), split work finer
// (QPERH=16 -> 1024 blocks) so the scheduler streams ~3 blocks/CU and
// rebalances the per-head skew.
#define DDIM 512
#define VDIM 16
#define EHEADS 64
#define NVOX 65536
#define QPERH 16
#define SLICE (NVOX / QPERH)          // 4096 voxels per block slice
#define NBLOCKS (EHEADS * QPERH)      // 1024 blocks -> scheduler-refilled
#define WRANGE (SLICE / 4)            // 1024 voxels per wave
#define WCAP 256                      // per-wave list cap (mean ~16, >25 sigma)
#define KSTEPS 16                     // K=32 MFMA steps
#define KHALF 8                       // k-steps per register half (VGPR cap)

typedef __bf16  bf16x8  __attribute__((ext_vector_type(8)));
typedef float   floatx4 __attribute__((ext_vector_type(4)));

__global__ __launch_bounds__(256, 3) void fused_decode_kernel(
    const int*   __restrict__ btg,   // (NVOX,)
    const int*   __restrict__ b2h,   // (256,)
    const float* __restrict__ x,     // (NVOX, D)
    const float* __restrict__ Wh,    // (E, V, D)
    const float* __restrict__ bh,    // (E, V)
    float*       __restrict__ out)   // (NVOX, V)
{
    __shared__ int    lut[256];                   // 1 KB
    __shared__ bf16x8 Wfrag[KSTEPS * 64];         // 16 KB, MFMA fragment order
    __shared__ int    wlist[4][WCAP];             // 4 KB, per-wave lists

    const int tid  = threadIdx.x;
    const int lane = tid & 63;
    const int wv   = tid >> 6;                    // wave in block (0..3)
    const int e    = blockIdx.x >> 4;             // head
    const int q    = blockIdx.x & (QPERH - 1);    // slice
    const int m    = lane & 15;
    const int quad = lane >> 4;

    lut[tid] = b2h[tid];

    // ---- Stage W[e] -> LDS in fragment order (bf16), once per block -------
    // Wfrag[k0*64 + ln] = W[e][ln&15][k0*32 + (ln>>4)*8 + j], j=0..7
#pragma unroll
    for (int i = 0; i < 4; ++i) {
        const int f  = i * 256 + tid;
        const int k0 = f >> 6, ln = f & 63;
        const float* src = Wh + ((size_t)e * VDIM + (ln & 15)) * DDIM
                              + k0 * 32 + (ln >> 4) * 8;
        const floatx4 b0 = *(const floatx4*)src;
        const floatx4 b1 = *(const floatx4*)(src + 4);
        bf16x8 bf;
#pragma unroll
        for (int j = 0; j < 4; ++j) {
            bf[j] = (__bf16)b0[j]; bf[4 + j] = (__bf16)b1[j];
        }
        Wfrag[f] = bf;
    }
    __syncthreads();                              // ONLY barrier in the kernel

    // ---- Per-wave atomic-free scan: register cursor + ballot prefix --------
    const int wbase = q * SLICE + wv * WRANGE;
    int cnt = 0;
#pragma unroll
    for (int i = 0; i < WRANGE / 64; ++i) {       // 16 iterations, full unroll
        const int n = wbase + i * 64 + lane;      // wave-contiguous btg read
        const bool match = (lut[btg[n]] == e);
        const unsigned long long mk = __ballot(match);
        if (match) {
            const int p = cnt + __popcll(mk & ((1ull << lane) - 1ull));
            if (p < WCAP) wlist[wv][p] = n;
        }
        cnt += __popcll(mk);
    }
    if (cnt > WCAP) cnt = WCAP;

    const float bv = bh[e * VDIM + m];
    const int ntiles = (cnt + 15) >> 4;

    // ---- Decode: direct-to-VGPR A loads, compiler-counted vmcnt ------------
    // A-fragment for lane l, kstep k: row (l&15), cols k*32 + (l>>4)*8 .. +8
    // = two float4 loads off one per-lane base with immediate offsets.
    for (int t = 0; t < ntiles; ++t) {
        const int rs = t * 16;
        int rm = rs + m;
        if (rm >= cnt) rm = cnt - 1;              // clamp tail (stores guarded)
        const int idx_m = wlist[wv][rm];          // lane L holds row L&15
        const float* rowp = x + (size_t)idx_m * DDIM + (quad << 3);

        floatx4 acc = {0.f, 0.f, 0.f, 0.f};
#pragma unroll
        for (int h = 0; h < 2; ++h) {
            bf16x8 af[KHALF];
#pragma unroll
            for (int k = 0; k < KHALF; ++k) {     // 16 independent dwordx4
                const float* p = rowp + (h * KHALF + k) * 32;
                const floatx4 a0 = *(const floatx4*)p;
                const floatx4 a1 = *(const floatx4*)(p + 4);
                bf16x8 tt;
#pragma unroll
                for (int j = 0; j < 4; ++j) {
                    tt[j] = (__bf16)a0[j]; tt[4 + j] = (__bf16)a1[j];
                }
                af[k] = tt;
            }
#pragma unroll
            for (int k = 0; k < KHALF; ++k)
                acc = __builtin_amdgcn_mfma_f32_16x16x32_bf16(
                          af[k], Wfrag[(h * KHALF + k) * 64 + lane], acc, 0, 0, 0);
        }

        // D: col = m (output v), row = quad*4 + r (voxel within tile)
#pragma unroll
        for (int r = 0; r < 4; ++r) {
            const int o = rs + quad * 4 + r;
            if (o < cnt)
                out[(size_t)wlist[wv][o] * VDIM + m] = acc[r] + bv;
        }
    }
}

extern "C" void kernel_launch(void* const* d_in, const int* in_sizes, int n_in,
                              void* d_out, int out_size, void* d_ws, size_t ws_size,
                              hipStream_t stream)
{
    const int*   btg = (const int*)d_in[0];
    const float* x   = (const float*)d_in[1];
    const float* Wh  = (const float*)d_in[2];
    const float* bh  = (const float*)d_in[3];
    const int*   b2h = (const int*)d_in[4];
    float*       out = (float*)d_out;
    (void)d_ws; (void)ws_size; (void)in_sizes; (void)n_in; (void)out_size;

    fused_decode_kernel<<<NBLOCKS, 256, 0, stream>>>(btg, b2h, x, Wh, bh, out);
}

// Round 4
// 210.698 us; speedup vs baseline: 1.0715x; 1.0648x over previous
//
#include <hip/hip_runtime.h>
#include <hip/hip_bf16.h>

// Problem: B,W,H,L = 2,32,32,32 -> N=65536 voxels; D=512, E=64 heads, V=16.
// Round-15 (= R13 resubmit #2; R13/R14 benches were infra failures — push
// timing showed the container degrading before launch; source audited clean
// for fault/hang). R12's VGPR_Count=60 proved the pre-RA scheduler sank
// every load pair next to its bf16 convert (16 serial HBM trips per tile,
// ~30 B/wave in flight, per-CU BW 5 GB/s). Pin the schedule: issue 16
// dwordx4 into live floatx4 regs, then sched_barrier(0), then convert+MFMA
// -> first use waits vmcnt(15). Same for the btg scan. Half-tile (8 k-step)
// staging keeps raw pressure ~64 regs -> __launch_bounds__(256,4) (cap 128)
// -> 4 blocks/CU, all 1024 blocks resident, 16 KB/wave in flight even in
// the heavy-head tail.
#define DDIM 512
#define VDIM 16
#define EHEADS 64
#define NVOX 65536
#define QPERH 16
#define SLICE (NVOX / QPERH)          // 4096 voxels per block slice
#define NBLOCKS (EHEADS * QPERH)      // 1024 blocks = 4/CU, all resident
#define WRANGE (SLICE / 4)            // 1024 voxels per wave
#define WCAP 256                      // per-wave list cap (mean ~16, >25 sigma)
#define KSTEPS 16                     // K=32 MFMA steps
#define KHALF 8                       // k-steps per staged half (64 raw VGPRs)

typedef __bf16  bf16x8  __attribute__((ext_vector_type(8)));
typedef float   floatx4 __attribute__((ext_vector_type(4)));

__global__ __launch_bounds__(256, 4) void fused_decode_kernel(
    const int*   __restrict__ btg,   // (NVOX,)
    const int*   __restrict__ b2h,   // (256,)
    const float* __restrict__ x,     // (NVOX, D)
    const float* __restrict__ Wh,    // (E, V, D)
    const float* __restrict__ bh,    // (E, V)
    float*       __restrict__ out)   // (NVOX, V)
{
    __shared__ int    lut[256];                   // 1 KB
    __shared__ bf16x8 Wfrag[KSTEPS * 64];         // 16 KB, MFMA fragment order
    __shared__ int    wlist[4][WCAP];             // 4 KB, per-wave lists

    const int tid  = threadIdx.x;
    const int lane = tid & 63;
    const int wv   = tid >> 6;                    // wave in block (0..3)
    const int e    = blockIdx.x >> 4;             // head
    const int q    = blockIdx.x & (QPERH - 1);    // slice
    const int m    = lane & 15;
    const int quad = lane >> 4;

    lut[tid] = b2h[tid];

    // ---- Stage W[e] -> LDS in fragment order (bf16), once per block -------
    // Wfrag[k0*64 + ln] = W[e][ln&15][k0*32 + (ln>>4)*8 + j], j=0..7
#pragma unroll
    for (int i = 0; i < 4; ++i) {
        const int f  = i * 256 + tid;
        const int k0 = f >> 6, ln = f & 63;
        const float* src = Wh + ((size_t)e * VDIM + (ln & 15)) * DDIM
                              + k0 * 32 + (ln >> 4) * 8;
        const floatx4 b0 = *(const floatx4*)src;
        const floatx4 b1 = *(const floatx4*)(src + 4);
        bf16x8 bf;
#pragma unroll
        for (int j = 0; j < 4; ++j) {
            bf[j] = (__bf16)b0[j]; bf[4 + j] = (__bf16)b1[j];
        }
        Wfrag[f] = bf;
    }
    __syncthreads();                              // ONLY barrier in the kernel

    // ---- Per-wave atomic-free scan: hoisted loads + ballot prefix ---------
    const int wbase = q * SLICE + wv * WRANGE;
    int bt[WRANGE / 64];
#pragma unroll
    for (int i = 0; i < WRANGE / 64; ++i)         // 16 independent loads
        bt[i] = btg[wbase + i * 64 + lane];
    __builtin_amdgcn_sched_barrier(0);            // keep them all in flight
    int cnt = 0;
#pragma unroll
    for (int i = 0; i < WRANGE / 64; ++i) {
        const bool match = (lut[bt[i]] == e);
        const unsigned long long mk = __ballot(match);
        if (match) {
            const int p = cnt + __popcll(mk & ((1ull << lane) - 1ull));
            if (p < WCAP) wlist[wv][p] = wbase + i * 64 + lane;
        }
        cnt += __popcll(mk);
    }
    if (cnt > WCAP) cnt = WCAP;

    const float bv = bh[e * VDIM + m];
    const int ntiles = (cnt + 15) >> 4;

    // ---- Decode: staged-register A loads, schedule pinned -----------------
    // A-fragment for lane l, kstep k: row (l&15), cols k*32 + (l>>4)*8 .. +8
    for (int t = 0; t < ntiles; ++t) {
        const int rs = t * 16;
        int rm = rs + m;
        if (rm >= cnt) rm = cnt - 1;              // clamp tail (stores guarded)
        const int idx_m = wlist[wv][rm];          // lane L holds row L&15
        const float* rowp = x + (size_t)idx_m * DDIM + (quad << 3);

        floatx4 acc = {0.f, 0.f, 0.f, 0.f};
#pragma unroll
        for (int h = 0; h < 2; ++h) {
            floatx4 ra[KHALF], rb[KHALF];
#pragma unroll
            for (int k = 0; k < KHALF; ++k) {     // 16 independent dwordx4
                const float* p = rowp + (h * KHALF + k) * 32;
                ra[k] = *(const floatx4*)p;
                rb[k] = *(const floatx4*)(p + 4);
            }
            __builtin_amdgcn_sched_barrier(0);    // all issued before any use
#pragma unroll
            for (int k = 0; k < KHALF; ++k) {
                bf16x8 af;
#pragma unroll
                for (int j = 0; j < 4; ++j) {
                    af[j]     = (__bf16)ra[k][j];
                    af[4 + j] = (__bf16)rb[k][j];
                }
                acc = __builtin_amdgcn_mfma_f32_16x16x32_bf16(
                          af, Wfrag[(h * KHALF + k) * 64 + lane], acc, 0, 0, 0);
            }
        }

        // D: col = m (output v), row = quad*4 + r (voxel within tile)
#pragma unroll
        for (int r = 0; r < 4; ++r) {
            const int o = rs + quad * 4 + r;
            if (o < cnt)
                out[(size_t)wlist[wv][o] * VDIM + m] = acc[r] + bv;
        }
    }
}

extern "C" void kernel_launch(void* const* d_in, const int* in_sizes, int n_in,
                              void* d_out, int out_size, void* d_ws, size_t ws_size,
                              hipStream_t stream)
{
    const int*   btg = (const int*)d_in[0];
    const float* x   = (const float*)d_in[1];
    const float* Wh  = (const float*)d_in[2];
    const float* bh  = (const float*)d_in[3];
    const int*   b2h = (const int*)d_in[4];
    float*       out = (float*)d_out;
    (void)d_ws; (void)ws_size; (void)in_sizes; (void)n_in; (void)out_size;

    fused_decode_kernel<<<NBLOCKS, 256, 0, stream>>>(btg, b2h, x, Wh, bh, out);
}